// Round 12
// baseline (64.300 us; speedup 1.0000x reference)
//
#include <hip/hip_runtime.h>
#include <hip/hip_bf16.h>

namespace {

constexpr int B_ = 4, L = 2048, H = 8, E = 64;
constexpr int RS = H * E;            // 512 floats: row stride in [B,L,H,E]
constexpr float CS = 0.125f * 1.44269504f;  // SCALE * log2(e): exp2-direct
constexpr float THR2 = 11.5f;        // defer-max threshold in log2 units

// ws layout: acc bf16-pairs as uints [4 slots][32 bh][8 pp][4096] ++ m ++ l (fp32)
constexpr size_t ACC_UINTS = (size_t)4 * 32 * 8 * 4096;  // 4,194,304 (x4B)
constexpr size_t MOFF = ACC_UINTS;                       // float offset
constexpr size_t MCNT = (size_t)4 * 32 * 8 * 128;        // 131,072
constexpr size_t LOFF = MOFF + MCNT;
constexpr size_t WS_FLOATS = LOFF + MCNT;                // 17.8 MB (ws >= 34.1 proven)

typedef __attribute__((ext_vector_type(8))) short bf16x8;
typedef __attribute__((ext_vector_type(4))) float f32x4;

__device__ inline unsigned cvt2(float a, float b) {
  __hip_bfloat162 hh = __float22bfloat162_rn(make_float2(a, b));  // v_cvt_pk_bf16_f32
  union { __hip_bfloat162 h; unsigned u; } c; c.h = hh; return c.u;
}
__device__ inline float bf2f(unsigned short u) {
  union { unsigned u; float f; } c; c.u = (unsigned)u << 16; return c.f;
}

// 4-way split-K over pairs (g, v=15-g) of 128-row q-groups (1024 blocks,
// 4/CU, 32 waves/CU). g<=4: role0 = g complete (direct O), roles1-3 = v
// 3-way (slots 1,2,3). g>=5: roles0-1 = g 2-way (slots 0,1), roles2-3 =
// v 2-way (slots 2,3). Hot loop identical to round 11 (proven): swapped
// S^T = K*Q^T, exp2-domain softmax, per-lane lsum, defer-max, V frag =
// one b128, conflict-free swizzles.
__global__ __launch_bounds__(512)
void fa_split(const float* __restrict__ Q, const float* __restrict__ K,
              const float* __restrict__ V, float* __restrict__ O,
              float* __restrict__ ws, int splitMode)
{
  const int tid  = (int)threadIdx.x;
  const int lane = tid & 63;
  const int wv   = tid >> 6;
  const int bi   = (int)blockIdx.x;
  const int bh   = bi & 31;                 // low bits -> XCD L2 locality
  const int pp   = (bi >> 5) & 7;
  const int role = bi >> 8;
  const int b = bh >> 3, h = bh & 7;
  const int ln = lane & 15, lg = lane >> 4, d0 = lg * 4;

  const int g = pp, v = 15 - pp;
  const int b0 = 2 * g + 2, nsv = 32 - 2 * g;

  int grp, kLo, kHi, slot = -1; bool fin = false;
  if (splitMode) {
    if (g <= 4) {
      if (role == 0) { grp = g; kLo = 0; kHi = b0; fin = true; }
      else {
        const int c1 = (nsv + 2) / 3, c2 = c1 + (nsv - c1 + 1) / 2;
        grp = v; slot = role;
        if (role == 1)      { kLo = 0;  kHi = c1; }
        else if (role == 2) { kLo = c1; kHi = c2; }
        else                { kLo = c2; kHi = nsv; }
      }
    } else {
      const int hh = b0 / 2, hv = nsv / 2;
      if (role == 0)      { grp = g; kLo = 0;  kHi = hh;  slot = 0; }
      else if (role == 1) { grp = g; kLo = hh; kHi = b0;  slot = 1; }
      else if (role == 2) { grp = v; kLo = 0;  kHi = hv;  slot = 2; }
      else                { grp = v; kLo = hv; kHi = nsv; slot = 3; }
    }
  } else {  // fallback: 512 blocks, both roles complete (imbalanced, correct)
    if (role == 0) { grp = g; kLo = 0; kHi = b0; }
    else           { grp = v; kLo = 0; kHi = nsv; }
    fin = true;
  }

  const size_t base = (size_t)b * L * RS + (size_t)h * E;
  const float* Qb = Q + base;
  const float* Kb = K + base;
  const float* Vb = V + base;
  float*       Ob = O + base;

  __shared__ __align__(16) unsigned char KT[2][64 * 128];
  __shared__ __align__(16) unsigned char VT[2][64 * 128];

  // ---- staging (identical to round 11) ----
  const int vdd = tid & 63, vc = tid >> 6;          // V: dim vdd, chunk vc
  const int vkb = 4 * vc + ((vc >> 2) << 4);        // keys vkb..+3, vkb+16..+19
  const int kky = tid >> 3, kc = tid & 7;           // K: key kky, dims 8kc..+7
  float vr[8]; float4 kr0, kr1;

  auto stage_load = [&](int ks) {
    const int kv0 = ks * 64;
    const float* vp = Vb + (size_t)(kv0 + vkb) * RS + vdd;
#pragma unroll
    for (int j = 0; j < 4; ++j) vr[j] = vp[(size_t)j * RS];
#pragma unroll
    for (int j = 0; j < 4; ++j) vr[4 + j] = vp[(size_t)(16 + j) * RS];
    const float* kp = Kb + (size_t)(kv0 + kky) * RS + 8 * kc;
    kr0 = *(const float4*)kp; kr1 = *(const float4*)(kp + 4);
  };
  auto stage_write = [&](int bufI) {
    union { uint4 q; unsigned u[4]; } w;
    w.u[0] = cvt2(vr[0], vr[1]); w.u[1] = cvt2(vr[2], vr[3]);
    w.u[2] = cvt2(vr[4], vr[5]); w.u[3] = cvt2(vr[6], vr[7]);
    *(uint4*)(VT[bufI] + vdd * 128 + 16 * (vc ^ (vdd & 7))) = w.q;
    union { uint4 q; unsigned u[4]; } y;
    y.u[0] = cvt2(kr0.x, kr0.y); y.u[1] = cvt2(kr0.z, kr0.w);
    y.u[2] = cvt2(kr1.x, kr1.y); y.u[3] = cvt2(kr1.z, kr1.w);
    *(uint4*)(KT[bufI] + kky * 128 + 16 * (kc ^ (kky & 7))) = y.q;
  };

  const int qrow0 = grp * 128 + wv * 16;
  const int nsW   = (qrow0 + 79) >> 6;       // this wave's causal step count

  // Q fragments, pre-scaled by CS (exp2 domain)
  bf16x8 qf0, qf1;
  {
    const float* qp = Qb + (size_t)(qrow0 + ln) * RS + 8 * lg;
    float4 a = *(const float4*)qp,        c = *(const float4*)(qp + 4);
    float4 d = *(const float4*)(qp + 32), e = *(const float4*)(qp + 36);
    union { bf16x8 v8; unsigned u[4]; } r0, r1;
    r0.u[0] = cvt2(a.x * CS, a.y * CS); r0.u[1] = cvt2(a.z * CS, a.w * CS);
    r0.u[2] = cvt2(c.x * CS, c.y * CS); r0.u[3] = cvt2(c.z * CS, c.w * CS);
    r1.u[0] = cvt2(d.x * CS, d.y * CS); r1.u[1] = cvt2(d.z * CS, d.w * CS);
    r1.u[2] = cvt2(e.x * CS, e.y * CS); r1.u[3] = cvt2(e.z * CS, e.w * CS);
    qf0 = r0.v8; qf1 = r1.v8;
  }

  f32x4 acc[4];
#pragma unroll
  for (int nt = 0; nt < 4; ++nt) acc[nt] = (f32x4){0.f, 0.f, 0.f, 0.f};
  float m = -1e30f, lsum = 0.f;              // lsum: per-lane partial

  stage_load(kLo);
  stage_write(0);
  __syncthreads();
  int buf = 0;

  for (int ks = kLo; ks < kHi; ++ks) {
    const bool haveNext = (ks + 1) < kHi;
    if (haveNext) stage_load(ks + 1);        // T14: issue early

    if (ks < nsW) {
      const unsigned char* Kt = KT[buf];
      const int swzr = 16 * (ln & 7);

      f32x4 st[4];
#pragma unroll
      for (int kt = 0; kt < 4; ++kt) {
        const unsigned char* kr = Kt + (16 * kt + ln) * 128;
        const bf16x8 kfa = *(const bf16x8*)(kr + ((16 * lg) ^ swzr));
        const bf16x8 kfb = *(const bf16x8*)(kr + ((16 * lg + 64) ^ swzr));
        f32x4 s = (f32x4){0.f, 0.f, 0.f, 0.f};
        s = __builtin_amdgcn_mfma_f32_16x16x32_bf16(kfa, qf0, s, 0, 0, 0);
        s = __builtin_amdgcn_mfma_f32_16x16x32_bf16(kfb, qf1, s, 0, 0, 0);
        st[kt] = s;
      }

      float x[16];
#pragma unroll
      for (int kt = 0; kt < 4; ++kt)
#pragma unroll
        for (int r = 0; r < 4; ++r) x[4 * kt + r] = st[kt][r];

      if (ks == nsW - 1) {                   // diagonal tile
        const int kv0 = ks * 64;
        const int qr = qrow0 + ln;
#pragma unroll
        for (int kt = 0; kt < 4; ++kt)
#pragma unroll
          for (int r = 0; r < 4; ++r) {
            const int key = kv0 + 16 * kt + d0 + r;
            if (key > qr) x[4 * kt + r] = -1e30f;
          }
      }

      // per-lane max (tree); rescale only on rare threshold breach
      float t8[8];
#pragma unroll
      for (int e = 0; e < 8; ++e) t8[e] = fmaxf(x[e], x[8 + e]);
      float t4a = fmaxf(t8[0], t8[4]), t4b = fmaxf(t8[1], t8[5]);
      float t4c = fmaxf(t8[2], t8[6]), t4d = fmaxf(t8[3], t8[7]);
      float mx = fmaxf(fmaxf(t4a, t4b), fmaxf(t4c, t4d));

      if (!__all(mx <= m + THR2)) {
        float gm = fmaxf(mx, __shfl_xor(mx, 16, 64));
        gm = fmaxf(gm, __shfl_xor(gm, 32, 64));
        const float newm = fmaxf(m, gm);
        const float sc = __builtin_exp2f(m - newm);
        lsum *= sc;
        float scr[4];
#pragma unroll
        for (int r = 0; r < 4; ++r) scr[r] = __shfl(sc, d0 + r, 64);
#pragma unroll
        for (int nt = 0; nt < 4; ++nt) {
          acc[nt][0] *= scr[0]; acc[nt][1] *= scr[1];
          acc[nt][2] *= scr[2]; acc[nt][3] *= scr[3];
        }
        m = newm;
      }

      float p[16];
#pragma unroll
      for (int e = 0; e < 16; ++e) p[e] = __builtin_exp2f(x[e] - m);
      {
        float s8[8];
#pragma unroll
        for (int e = 0; e < 8; ++e) s8[e] = p[e] + p[8 + e];
        float s4a = s8[0] + s8[4], s4b = s8[1] + s8[5];
        float s4c = s8[2] + s8[6], s4d = s8[3] + s8[7];
        lsum += (s4a + s4b) + (s4c + s4d);
      }

      // PV: 2 key-groups x 4 dim-tiles, V frag = one b128
      const unsigned char* Vt = VT[buf];
#pragma unroll
      for (int kg = 0; kg < 2; ++kg) {
        union { bf16x8 v8; unsigned u[4]; } pf;
#pragma unroll
        for (int j = 0; j < 4; ++j)
          pf.u[j] = cvt2(p[8 * kg + 2 * j], p[8 * kg + 2 * j + 1]);
#pragma unroll
        for (int nt = 0; nt < 4; ++nt) {
          const int row = ln + 16 * nt;
          const bf16x8 vf = *(const bf16x8*)(
              Vt + row * 128 + 16 * ((lg + 4 * kg) ^ (ln & 7)));
          acc[nt] = __builtin_amdgcn_mfma_f32_16x16x32_bf16(pf.v8, vf, acc[nt], 0, 0, 0);
        }
      }
    }

    if (haveNext) stage_write(buf ^ 1);
    __syncthreads();
    buf ^= 1;
  }

  // ---- epilogue ----
  float ls = lsum + __shfl_xor(lsum, 16, 64);
  ls += __shfl_xor(ls, 32, 64);
  if (fin) {
    const float il = 1.0f / ls;
    float inv[4];
#pragma unroll
    for (int r = 0; r < 4; ++r) inv[r] = __shfl(il, d0 + r, 64);
#pragma unroll
    for (int nt = 0; nt < 4; ++nt)
#pragma unroll
      for (int r = 0; r < 4; ++r)
        Ob[(size_t)(qrow0 + d0 + r) * RS + (ln + 16 * nt)] = acc[nt][r] * inv[r];
  } else {
    // bf16-pair packed partial: uint j = nt*2+rp holds (acc[nt][2rp], acc[nt][2rp+1])
    unsigned* wsu = (unsigned*)ws;
    const size_t ubase =
        ((((size_t)slot * 32 + bh) * 8 + pp) * 8 + wv) * 512 + (size_t)lane * 8;
    uint4 u0, u1;
    u0.x = cvt2(acc[0][0], acc[0][1]); u0.y = cvt2(acc[0][2], acc[0][3]);
    u0.z = cvt2(acc[1][0], acc[1][1]); u0.w = cvt2(acc[1][2], acc[1][3]);
    u1.x = cvt2(acc[2][0], acc[2][1]); u1.y = cvt2(acc[2][2], acc[2][3]);
    u1.z = cvt2(acc[3][0], acc[3][1]); u1.w = cvt2(acc[3][2], acc[3][3]);
    *(uint4*)(wsu + ubase)     = u0;
    *(uint4*)(wsu + ubase + 4) = u1;
    if (lane < 16) {
      const size_t mi = (((size_t)slot * 32 + bh) * 8 + pp) * 128 + wv * 16 + lane;
      ws[MOFF + mi] = m;
      ws[LOFF + mi] = ls;
    }
  }
}

// Merge 2-3 partials per row for groups 5..15. Static slot table.
__global__ __launch_bounds__(256)
void fa_merge(const float* __restrict__ ws, float* __restrict__ O)
{
  const int bi  = (int)blockIdx.x;          // 11*32*8 = 2816
  const int sub = bi & 7;
  const int pr  = bi >> 3;                  // 0..351
  const int gi  = pr >> 5, bh = pr & 31;
  const int tid = (int)threadIdx.x;
  const int d4  = tid & 15;                 // dims 4*d4..+3
  const int row = sub * 16 + (tid >> 4);    // 0..127

  const int Gt[11] = {5,6,7, 8,9,10, 11,12,13,14,15};
  const int nS[11] = {2,2,2, 2,2,2, 3,3,3,3,3};
  const int S0[11] = {0,0,0, 2,2,2, 1,1,1,1,1};
  const int S1[11] = {1,1,1, 3,3,3, 2,2,2,2,2};
  const int S2[11] = {0,0,0, 0,0,0, 3,3,3,3,3};

  const int G  = Gt[gi];
  const int n  = nS[gi];
  const int pp = (G <= 7) ? G : (15 - G);
  int sl[3] = {S0[gi], S1[gi], S2[gi]};

  // m/l per slot
  float mv[3], lv[3];
#pragma unroll
  for (int i = 0; i < 3; ++i) {
    if (i < n) {
      const size_t mi = (((size_t)sl[i] * 32 + bh) * 8 + pp) * 128 + row;
      mv[i] = ws[MOFF + mi]; lv[i] = ws[LOFF + mi];
    } else { mv[i] = -1e30f; lv[i] = 0.f; }
  }
  float M = fmaxf(mv[0], mv[1]); if (n > 2) M = fmaxf(M, mv[2]);
  float w[3]; float den = 0.f;
#pragma unroll
  for (int i = 0; i < 3; ++i) {
    w[i] = (i < n) ? __builtin_exp2f(mv[i] - M) : 0.f;
    den += lv[i] * w[i];
  }
  const float inv = 1.0f / den;

  // acc gather: dims 4*d4..+3; value (row,dim) at lane lg*16+ln, uint nt*2+rp
  const int wvq = row >> 4, lgq = (row & 15) >> 2, r = row & 3;
  const int rp = r >> 1, rlo = r & 1;
  const unsigned short* wsh = (const unsigned short*)ws;
  float o[4] = {0.f, 0.f, 0.f, 0.f};
#pragma unroll
  for (int i = 0; i < 3; ++i) {
    if (i >= n) break;
    const size_t base_u =
        ((((size_t)sl[i] * 32 + bh) * 8 + pp) * 8 + wvq) * 512;
#pragma unroll
    for (int j = 0; j < 4; ++j) {
      const int dim = 4 * d4 + j;
      const int ln = dim & 15, nt = dim >> 4;
      const size_t ua = base_u + (size_t)(lgq * 16 + ln) * 8 + nt * 2 + rp;
      o[j] += bf2f(wsh[ua * 2 + rlo]) * w[i];
    }
  }

  const int b = bh >> 3, h = bh & 7;
  const size_t off = ((size_t)(b * L + G * 128 + row) * H + h) * E + 4 * d4;
  float4 ov; ov.x = o[0] * inv; ov.y = o[1] * inv; ov.z = o[2] * inv; ov.w = o[3] * inv;
  *(float4*)(O + off) = ov;
}

} // namespace

extern "C" void kernel_launch(void* const* d_in, const int* in_sizes, int n_in,
                              void* d_out, int out_size, void* d_ws, size_t ws_size,
                              hipStream_t stream) {
  const float* Q = (const float*)d_in[0];
  const float* K = (const float*)d_in[1];
  const float* V = (const float*)d_in[2];
  float* O = (float*)d_out;
  (void)in_sizes; (void)n_in; (void)out_size;

  const bool split = ws_size >= WS_FLOATS * sizeof(float);
  if (split) {
    fa_split<<<1024, 512, 0, stream>>>(Q, K, V, O, (float*)d_ws, 1);
    fa_merge<<<2816, 256, 0, stream>>>((const float*)d_ws, O);
  } else {
    fa_split<<<512, 512, 0, stream>>>(Q, K, V, O, (float*)d_ws, 0);
  }
}

// Round 13
// 60.528 us; speedup vs baseline: 1.0623x; 1.0623x over previous
//
#include <hip/hip_runtime.h>
#include <hip/hip_bf16.h>

namespace {

constexpr int B_ = 4, L = 2048, H = 8, E = 64;
constexpr int RS = H * E;            // 512 floats: row stride in [B,L,H,E]
constexpr float CS = 0.125f * 1.44269504f;  // SCALE * log2(e): exp2-direct
constexpr float THR2 = 11.5f;        // defer-max threshold in log2 units

// split-K partials (floats): acc[2][32][1024rows][64] ++ m ++ l  (== R11 layout)
constexpr size_t ACCF = (size_t)2 * 32 * 8 * 128 * 64;
constexpr size_t MOFF = ACCF;
constexpr size_t PART_ROWS = (size_t)32 * 8 * 128;     // 32768 rows per part
constexpr size_t LOFF = MOFF + 2 * PART_ROWS;
constexpr size_t PART_FLOATS = LOFF + 2 * PART_ROWS;   // ~17.3 MB

typedef __attribute__((ext_vector_type(8)))  short bf16x8;
typedef __attribute__((ext_vector_type(16))) float f32x16;

__device__ inline unsigned cvt2(float a, float b) {
  __hip_bfloat162 hh = __float22bfloat162_rn(make_float2(a, b));  // v_cvt_pk_bf16_f32
  union { __hip_bfloat162 h; unsigned u; } c; c.h = hh; return c.u;
}

// Block = 8 waves x 32 q-rows = 256-row group pair (g, 7-g); step counts
// (4g+4) + (32-4g... =4(7-g)+4) sum to 36 -> two UNIFORM 18-step roles.
// role0: group g complete (direct O) + head of v=7-g (partial slot 0).
// role1: tail of v (partial slot 1). 256 blocks, 512 thr, 1/CU, uniform.
// 32x32x16 MFMA. Swapped S^T = K*Q^T: C col = lane&31 = q-row, per-lane 32
// scores. P -> PV A-operand via cvt_pk + v_permlane32_swap_b32 (guide SB).
// K LDS [key][chunk c @16*(c^(key&7))] = dims 8c..+7.
// V LDS [dim][chunk c @16*(c^(dim&7))] = keys 8c..+7 (contiguous).
__global__ __launch_bounds__(512)
void fa_split(const float* __restrict__ Q, const float* __restrict__ K,
              const float* __restrict__ V, float* __restrict__ O,
              float* __restrict__ ws, int splitMode)
{
  const int tid  = (int)threadIdx.x;
  const int lane = tid & 63;
  const int wv   = tid >> 6;
  const int bi   = (int)blockIdx.x;
  const int bh   = bi & 31;                 // low bits -> XCD L2 locality
  const int pq   = (bi >> 5) & 3;           // pair index 0..3
  const int role = splitMode ? (bi >> 7) : 0;
  const int b = bh >> 3, h = bh & 7;
  const int ln32 = lane & 31, hb = lane >> 5;
  const int rsw  = ln32 & 7;                // row swizzle bits (same for +32 rows)

  const int g = pq, v = 7 - pq;
  const int ng = 4 * g + 4;                 // ng + nv = 36

  int total, ph1, grpA, k0A, grpB; bool finA, finB; int part;
  if (splitMode) {
    if (role == 0) { total = 18; ph1 = ng;   grpA = g; k0A = 0;       finA = true;  grpB = v; finB = false; part = 0; }
    else           { total = 18; ph1 = 1000; grpA = v; k0A = 18 - ng; finA = false; grpB = 0; finB = false; part = 1; }
  } else {
    total = 36; ph1 = ng; grpA = g; k0A = 0; finA = true; grpB = v; finB = true; part = 0;
  }

  const size_t base = (size_t)b * L * RS + (size_t)h * E;
  const float* Qb = Q + base;
  const float* Kb = K + base;
  const float* Vb = V + base;
  float*       Ob = O + base;

  __shared__ __align__(16) unsigned char KT[2][64 * 128];
  __shared__ __align__(16) unsigned char VT[2][64 * 128];

  // ---- staging: 512 threads, one uint4 LDS write each for K and V ----
  const int vdd = tid & 63, vc = tid >> 6;          // V: dim vdd, keys 8vc..+7
  const int kky = tid >> 3, kc = tid & 7;           // K: key kky, dims 8kc..+7
  float vr[8]; float4 kr0, kr1;

  auto stage_load = [&](int ks) {
    const int kv0 = ks * 64;
    const float* vp = Vb + (size_t)(kv0 + 8 * vc) * RS + vdd;
#pragma unroll
    for (int j = 0; j < 8; ++j) vr[j] = vp[(size_t)j * RS];
    const float* kp = Kb + (size_t)(kv0 + kky) * RS + 8 * kc;
    kr0 = *(const float4*)kp; kr1 = *(const float4*)(kp + 4);
  };
  auto stage_write = [&](int bufI) {
    union { uint4 q; unsigned u[4]; } w;
    w.u[0] = cvt2(vr[0], vr[1]); w.u[1] = cvt2(vr[2], vr[3]);
    w.u[2] = cvt2(vr[4], vr[5]); w.u[3] = cvt2(vr[6], vr[7]);
    *(uint4*)(VT[bufI] + vdd * 128 + 16 * (vc ^ (vdd & 7))) = w.q;
    union { uint4 q; unsigned u[4]; } y;
    y.u[0] = cvt2(kr0.x, kr0.y); y.u[1] = cvt2(kr0.z, kr0.w);
    y.u[2] = cvt2(kr1.x, kr1.y); y.u[3] = cvt2(kr1.z, kr1.w);
    *(uint4*)(KT[bufI] + kky * 128 + 16 * (kc ^ (kky & 7))) = y.q;
  };

  // ---- per-phase state ----
  int grp = grpA; bool curFin = finA;
  int qrow0 = grp * 256 + wv * 32;
  int nsW   = 4 * grp + 1 + (wv >> 1);

  bf16x8 qf[4];
  auto load_q = [&]() {   // lane: q-row qrow0+ln32, dims 16*ds + 8*hb + j
    const float* qp = Qb + (size_t)(qrow0 + ln32) * RS + 8 * hb;
#pragma unroll
    for (int ds = 0; ds < 4; ++ds) {
      float4 a = *(const float4*)(qp + 16 * ds);
      float4 c = *(const float4*)(qp + 16 * ds + 4);
      union { bf16x8 v8; unsigned u[4]; } r;
      r.u[0] = cvt2(a.x * CS, a.y * CS); r.u[1] = cvt2(a.z * CS, a.w * CS);
      r.u[2] = cvt2(c.x * CS, c.y * CS); r.u[3] = cvt2(c.z * CS, c.w * CS);
      qf[ds] = r.v8;
    }
  };
  load_q();

  f32x16 zero;
#pragma unroll
  for (int i = 0; i < 16; ++i) zero[i] = 0.f;
  f32x16 accA = zero, accB = zero;          // dims 0-31 / 32-63
  float m = -1e30f, lsum = 0.f;             // per-lane (half the row's keys)

  auto epilogue = [&]() {
    float ls = lsum + __shfl_xor(lsum, 32, 64);   // row total
    if (curFin) {
      const float il = 1.0f / ls;
#pragma unroll
      for (int r2 = 0; r2 < 16; ++r2) {
        const int row = (r2 & 3) + 8 * (r2 >> 2) + 4 * hb;
        const float inv = __shfl(il, row, 64);
        Ob[(size_t)(qrow0 + row) * RS + ln32]      = accA[r2] * inv;
        Ob[(size_t)(qrow0 + row) * RS + 32 + ln32] = accB[r2] * inv;
      }
    } else {
      const size_t rb = ((size_t)part * 32 + bh) * 1024 + (size_t)(grp - 4) * 256;
#pragma unroll
      for (int r2 = 0; r2 < 16; ++r2) {
        const int row = (r2 & 3) + 8 * (r2 >> 2) + 4 * hb;
        const size_t lr = rb + wv * 32 + row;
        ws[lr * 64 + ln32]      = accA[r2];
        ws[lr * 64 + 32 + ln32] = accB[r2];
      }
      if (lane < 32) {
        ws[MOFF + rb + wv * 32 + lane] = m;
        ws[LOFF + rb + wv * 32 + lane] = ls;
      }
    }
  };

  stage_load(k0A);
  stage_write(0);
  __syncthreads();
  int buf = 0;

  for (int sb = 0; sb < total; ++sb) {
    const bool haveNext = (sb + 1) < total;
    if (haveNext) {
      const int sn = sb + 1;
      stage_load((sn < ph1) ? (k0A + sn) : (sn - ph1));   // T14: issue early
    }
    const int kstep = (sb < ph1) ? (k0A + sb) : (sb - ph1);

    if (kstep < nsW) {
      const unsigned char* Kt = KT[buf];

      // ---- QK^T: 2 key-tiles x 4 k-slots of 32x32x16 ----
      f32x16 st0 = zero, st1 = zero;
#pragma unroll
      for (int ds = 0; ds < 4; ++ds) {
        const int ch = 16 * ((2 * ds + hb) ^ rsw);
        const bf16x8 kf0 = *(const bf16x8*)(Kt + ln32 * 128 + ch);
        const bf16x8 kf1 = *(const bf16x8*)(Kt + (32 + ln32) * 128 + ch);
        st0 = __builtin_amdgcn_mfma_f32_32x32x16_bf16(kf0, qf[ds], st0, 0, 0, 0);
        st1 = __builtin_amdgcn_mfma_f32_32x32x16_bf16(kf1, qf[ds], st1, 0, 0, 0);
      }

      float x[32];
#pragma unroll
      for (int r2 = 0; r2 < 16; ++r2) { x[r2] = st0[r2]; x[16 + r2] = st1[r2]; }

      if (kstep == nsW - 1) {                // diagonal tile
        const int kv0 = kstep * 64;
        const int qr = qrow0 + ln32;
#pragma unroll
        for (int e = 0; e < 32; ++e) {
          const int key = kv0 + 32 * (e >> 4) + 8 * ((e >> 2) & 3) + (e & 3) + 4 * hb;
          if (key > qr) x[e] = -1e30f;
        }
      }

      // ---- per-lane max tree (31 ops), rescale only on rare breach ----
      float t16[16];
#pragma unroll
      for (int e = 0; e < 16; ++e) t16[e] = fmaxf(x[e], x[16 + e]);
      float t8[8];
#pragma unroll
      for (int e = 0; e < 8; ++e) t8[e] = fmaxf(t16[e], t16[8 + e]);
      float t4a = fmaxf(t8[0], t8[4]), t4b = fmaxf(t8[1], t8[5]);
      float t4c = fmaxf(t8[2], t8[6]), t4d = fmaxf(t8[3], t8[7]);
      const float mx = fmaxf(fmaxf(t4a, t4b), fmaxf(t4c, t4d));

      if (!__all(mx <= m + THR2)) {
        float gm = fmaxf(mx, __shfl_xor(mx, 32, 64));
        const float newm = fmaxf(m, gm);
        const float sc = __builtin_exp2f(m - newm);
        lsum *= sc;
        float scr[16];
#pragma unroll
        for (int r2 = 0; r2 < 16; ++r2) {
          const int row = (r2 & 3) + 8 * (r2 >> 2) + 4 * hb;
          scr[r2] = __shfl(sc, row, 64);
        }
#pragma unroll
        for (int r2 = 0; r2 < 16; ++r2) { accA[r2] *= scr[r2]; accB[r2] *= scr[r2]; }
        m = newm;
      }

      float p[32];
#pragma unroll
      for (int e = 0; e < 32; ++e) p[e] = __builtin_exp2f(x[e] - m);
      {
        float s16[16];
#pragma unroll
        for (int e = 0; e < 16; ++e) s16[e] = p[e] + p[16 + e];
        float s8[8];
#pragma unroll
        for (int e = 0; e < 8; ++e) s8[e] = s16[e] + s16[8 + e];
        const float sa = (s8[0] + s8[4]) + (s8[1] + s8[5]);
        const float sb2 = (s8[2] + s8[6]) + (s8[3] + s8[7]);
        lsum += sa + sb2;
      }

      // ---- P->A via cvt_pk + permlane32_swap; PV: 4 ks x 2 dim-tiles ----
      const unsigned char* Vt = VT[buf];
#pragma unroll
      for (int kt = 0; kt < 2; ++kt) {
#pragma unroll
        for (int hh2 = 0; hh2 < 2; ++hh2) {
          const int ks = 2 * kt + hh2;
          const int pb = 16 * kt + 8 * hh2;
          unsigned w0 = cvt2(p[pb + 0], p[pb + 1]);
          unsigned w2 = cvt2(p[pb + 4], p[pb + 5]);
          asm("v_permlane32_swap_b32 %0, %1" : "+v"(w0), "+v"(w2));
          unsigned w1 = cvt2(p[pb + 2], p[pb + 3]);
          unsigned w3 = cvt2(p[pb + 6], p[pb + 7]);
          asm("v_permlane32_swap_b32 %0, %1" : "+v"(w1), "+v"(w3));
          union { bf16x8 v8; unsigned u[4]; } A;
          A.u[0] = w0; A.u[1] = w1; A.u[2] = w2; A.u[3] = w3;
          const int chv = 16 * ((2 * ks + hb) ^ rsw);
          const bf16x8 vf0 = *(const bf16x8*)(Vt + ln32 * 128 + chv);
          const bf16x8 vf1 = *(const bf16x8*)(Vt + (32 + ln32) * 128 + chv);
          accA = __builtin_amdgcn_mfma_f32_32x32x16_bf16(A.v8, vf0, accA, 0, 0, 0);
          accB = __builtin_amdgcn_mfma_f32_32x32x16_bf16(A.v8, vf1, accB, 0, 0, 0);
        }
      }
    }

    if (sb == ph1 - 1) {                     // phase boundary (block-uniform)
      epilogue();
      accA = zero; accB = zero;
      m = -1e30f; lsum = 0.f;
      grp = grpB; curFin = finB;
      qrow0 = grp * 256 + wv * 32;
      nsW = 4 * grp + 1 + (wv >> 1);
      load_q();
    }

    if (haveNext) stage_write(buf ^ 1);
    __syncthreads();
    buf ^= 1;
  }

  epilogue();
}

// Combine the two split-K partials for rows 1024..2047 (VERBATIM from R11).
__global__ __launch_bounds__(256)
void fa_merge(const float* __restrict__ ws, float* __restrict__ O)
{
  const int idx = (int)blockIdx.x * 256 + (int)threadIdx.x;   // 0..524287
  const int d4  = idx & 15;
  const int row = (idx >> 4) & 127;
  const int vg  = (idx >> 11) & 7;
  const int bh  = idx >> 14;
  const size_t rbase = ((size_t)bh * 8 + vg) * 128 + row;

  const float m0 = ws[MOFF + rbase],             l0 = ws[LOFF + rbase];
  const float m1 = ws[MOFF + PART_ROWS + rbase], l1 = ws[LOFF + PART_ROWS + rbase];
  const float M  = fmaxf(m0, m1);
  const float e0 = __builtin_exp2f(m0 - M), e1 = __builtin_exp2f(m1 - M);
  const float inv = 1.0f / (l0 * e0 + l1 * e1);

  const float4 a0 = *(const float4*)(ws + rbase * 64 + 4 * d4);
  const float4 a1 = *(const float4*)(ws + PART_ROWS * 64 + rbase * 64 + 4 * d4);

  const int b = bh >> 3, h = bh & 7;
  const int orow = (8 + vg) * 128 + row;
  float4 o;
  o.x = (a0.x * e0 + a1.x * e1) * inv;
  o.y = (a0.y * e0 + a1.y * e1) * inv;
  o.z = (a0.z * e0 + a1.z * e1) * inv;
  o.w = (a0.w * e0 + a1.w * e1) * inv;
  *(float4*)(O + ((size_t)(b * L + orow) * H + h) * E + 4 * d4) = o;
}

} // namespace

extern "C" void kernel_launch(void* const* d_in, const int* in_sizes, int n_in,
                              void* d_out, int out_size, void* d_ws, size_t ws_size,
                              hipStream_t stream) {
  const float* Q = (const float*)d_in[0];
  const float* K = (const float*)d_in[1];
  const float* V = (const float*)d_in[2];
  float* O = (float*)d_out;
  (void)in_sizes; (void)n_in; (void)out_size;

  const bool split = ws_size >= PART_FLOATS * sizeof(float);
  if (split) {
    fa_split<<<256, 512, 0, stream>>>(Q, K, V, O, (float*)d_ws, 1);
    fa_merge<<<2048, 256, 0, stream>>>((const float*)d_ws, O);
  } else {
    fa_split<<<128, 512, 0, stream>>>(Q, K, V, O, (float*)d_ws, 0);
  }
}

// Round 14
// 60.235 us; speedup vs baseline: 1.0675x; 1.0049x over previous
//
#include <hip/hip_runtime.h>
#include <hip/hip_bf16.h>

namespace {

constexpr int B_ = 4, L = 2048, H = 8, E = 64;
constexpr int RS = H * E;            // 512 floats: row stride in [B,L,H,E]
constexpr float CS = 0.125f * 1.44269504f;  // SCALE * log2(e): exp2-direct
constexpr float THR2 = 11.5f;        // defer-max threshold in log2 units

// ws: acc bf16-pairs as uints [5 slots][32 bh][8 pp][8 wv][512] ++ m ++ l (fp32)
constexpr size_t ACC_UINTS = (size_t)5 * 32 * 8 * 8 * 512;   // 5,242,880
constexpr size_t MOFF = ACC_UINTS;                           // float offset
constexpr size_t MCNT = (size_t)5 * 32 * 8 * 128;            // 163,840
constexpr size_t LOFF = MOFF + MCNT;
constexpr size_t WS_FLOATS = LOFF + MCNT;                    // ~22.3 MB

typedef __attribute__((ext_vector_type(8))) short bf16x8;
typedef __attribute__((ext_vector_type(4))) float f32x4;

__device__ inline unsigned cvt2(float a, float b) {
  __hip_bfloat162 hh = __float22bfloat162_rn(make_float2(a, b));  // v_cvt_pk_bf16_f32
  union { __hip_bfloat162 h; unsigned u; } c; c.h = hh; return c.u;
}
__device__ inline float bf2f(unsigned short u) {
  union { unsigned u; float f; } c; c.u = (unsigned)u << 16; return c.f;
}

// Pair (g, v=15-g) of 128-row q-groups = 34 linear steps (g: 2g+2, then v:
// 32-2g). Cut at {0,9,18,26,34} -> 4 near-uniform chunks {9,9,8,8}; grid =
// 4 chunks x 8 pairs x 32 bh = 1024 blocks = 4/CU = 32 waves/CU. Boundary
// ng<=16 falls in chunk 0 or 1 -> <=5 segments/pair; slot(s)=|{starts<s}|,
// starts={0,9,18,26,ng}. Complete g-side (g<=3, chunk0) writes O direct;
// all other segments write bf16-packed partials (R12 format, proven).
// Hot loop VERBATIM from R11: swapped S^T=K*Q^T, exp2-domain, per-lane
// lsum, defer-max, V frag = one b128, conflict-free swizzles.
__global__ __launch_bounds__(512)
void fa_split(const float* __restrict__ Q, const float* __restrict__ K,
              const float* __restrict__ V, float* __restrict__ O,
              float* __restrict__ ws, int splitMode)
{
  const int tid  = (int)threadIdx.x;
  const int lane = tid & 63;
  const int wv   = tid >> 6;
  const int bi   = (int)blockIdx.x;
  const int bh   = bi & 31;                 // low bits -> XCD L2 locality
  const int pp   = (bi >> 5) & 7;
  const int chunk = bi >> 8;                // 0..3 (0 in fallback)
  const int b = bh >> 3, h = bh & 7;
  const int ln = lane & 15, lg = lane >> 4, d0 = lg * 4;

  const int g = pp, v = 15 - pp, ng = 2 * g + 2;

  int lo, hi;
  if (splitMode) {
    const int cuts[5] = {0, 9, 18, 26, 34};
    lo = cuts[chunk]; hi = cuts[chunk + 1];
  } else { lo = 0; hi = 34; }

  const bool hasB  = (ng > lo) && (ng < hi);
  const int  total = hi - lo;
  const int  ph1   = hasB ? (ng - lo) : 1000;
  const bool sideAg = (lo < ng);
  const int  grpA = sideAg ? g : v;
  const int  k0A  = sideAg ? lo : (lo - ng);
  const bool finA = sideAg ? (lo == 0 && hi >= ng) : false;
  const int  slotA = (lo > 0) + (lo > 9) + (lo > 18) + (lo > 26) + (lo > ng);
  const bool finB  = (hi == 34);            // true only in fallback
  const int  slotB = 1 + (ng > 9);

  const size_t base = (size_t)b * L * RS + (size_t)h * E;
  const float* Qb = Q + base;
  const float* Kb = K + base;
  const float* Vb = V + base;
  float*       Ob = O + base;

  __shared__ __align__(16) unsigned char KT[2][64 * 128];
  __shared__ __align__(16) unsigned char VT[2][64 * 128];

  // ---- staging (verbatim R11) ----
  const int vdd = tid & 63, vc = tid >> 6;          // V: dim vdd, chunk vc
  const int vkb = 4 * vc + ((vc >> 2) << 4);        // keys vkb..+3, vkb+16..+19
  const int kky = tid >> 3, kc = tid & 7;           // K: key kky, dims 8kc..+7
  float vr[8]; float4 kr0, kr1;

  auto stage_load = [&](int ks) {
    const int kv0 = ks * 64;
    const float* vp = Vb + (size_t)(kv0 + vkb) * RS + vdd;
#pragma unroll
    for (int j = 0; j < 4; ++j) vr[j] = vp[(size_t)j * RS];
#pragma unroll
    for (int j = 0; j < 4; ++j) vr[4 + j] = vp[(size_t)(16 + j) * RS];
    const float* kp = Kb + (size_t)(kv0 + kky) * RS + 8 * kc;
    kr0 = *(const float4*)kp; kr1 = *(const float4*)(kp + 4);
  };
  auto stage_write = [&](int bufI) {
    union { uint4 q; unsigned u[4]; } w;
    w.u[0] = cvt2(vr[0], vr[1]); w.u[1] = cvt2(vr[2], vr[3]);
    w.u[2] = cvt2(vr[4], vr[5]); w.u[3] = cvt2(vr[6], vr[7]);
    *(uint4*)(VT[bufI] + vdd * 128 + 16 * (vc ^ (vdd & 7))) = w.q;
    union { uint4 q; unsigned u[4]; } y;
    y.u[0] = cvt2(kr0.x, kr0.y); y.u[1] = cvt2(kr0.z, kr0.w);
    y.u[2] = cvt2(kr1.x, kr1.y); y.u[3] = cvt2(kr1.z, kr1.w);
    *(uint4*)(KT[bufI] + kky * 128 + 16 * (kc ^ (kky & 7))) = y.q;
  };

  // ---- per-phase state ----
  int grp = grpA; bool curFin = finA; int curSlot = slotA;
  int qrow0 = grp * 128 + wv * 16;
  int nsW   = (qrow0 + 79) >> 6;

  bf16x8 qf0, qf1;
  auto load_q = [&]() {                      // Q pre-scaled by CS (exp2 domain)
    const float* qp = Qb + (size_t)(qrow0 + ln) * RS + 8 * lg;
    float4 a = *(const float4*)qp,        c = *(const float4*)(qp + 4);
    float4 d = *(const float4*)(qp + 32), e = *(const float4*)(qp + 36);
    union { bf16x8 v8; unsigned u[4]; } r0, r1;
    r0.u[0] = cvt2(a.x * CS, a.y * CS); r0.u[1] = cvt2(a.z * CS, a.w * CS);
    r0.u[2] = cvt2(c.x * CS, c.y * CS); r0.u[3] = cvt2(c.z * CS, c.w * CS);
    r1.u[0] = cvt2(d.x * CS, d.y * CS); r1.u[1] = cvt2(d.z * CS, d.w * CS);
    r1.u[2] = cvt2(e.x * CS, e.y * CS); r1.u[3] = cvt2(e.z * CS, e.w * CS);
    qf0 = r0.v8; qf1 = r1.v8;
  };
  load_q();

  f32x4 acc[4];
#pragma unroll
  for (int nt = 0; nt < 4; ++nt) acc[nt] = (f32x4){0.f, 0.f, 0.f, 0.f};
  float m = -1e30f, lsum = 0.f;              // lsum: per-lane partial

  auto epilogue = [&]() {
    float ls = lsum + __shfl_xor(lsum, 16, 64);
    ls += __shfl_xor(ls, 32, 64);
    if (curFin) {
      const float il = 1.0f / ls;
      float inv[4];
#pragma unroll
      for (int r = 0; r < 4; ++r) inv[r] = __shfl(il, d0 + r, 64);
#pragma unroll
      for (int nt = 0; nt < 4; ++nt)
#pragma unroll
        for (int r = 0; r < 4; ++r)
          Ob[(size_t)(qrow0 + d0 + r) * RS + (ln + 16 * nt)] = acc[nt][r] * inv[r];
    } else {
      unsigned* wsu = (unsigned*)ws;
      const size_t ubase =
          ((((size_t)curSlot * 32 + bh) * 8 + pp) * 8 + wv) * 512 + (size_t)lane * 8;
      uint4 u0, u1;
      u0.x = cvt2(acc[0][0], acc[0][1]); u0.y = cvt2(acc[0][2], acc[0][3]);
      u0.z = cvt2(acc[1][0], acc[1][1]); u0.w = cvt2(acc[1][2], acc[1][3]);
      u1.x = cvt2(acc[2][0], acc[2][1]); u1.y = cvt2(acc[2][2], acc[2][3]);
      u1.z = cvt2(acc[3][0], acc[3][1]); u1.w = cvt2(acc[3][2], acc[3][3]);
      *(uint4*)(wsu + ubase)     = u0;
      *(uint4*)(wsu + ubase + 4) = u1;
      if (lane < 16) {
        const size_t mi = (((size_t)curSlot * 32 + bh) * 8 + pp) * 128 + wv * 16 + lane;
        ws[MOFF + mi] = m;
        ws[LOFF + mi] = ls;
      }
    }
  };

  stage_load(k0A);
  stage_write(0);
  __syncthreads();
  int buf = 0;

  for (int sb = 0; sb < total; ++sb) {
    const bool haveNext = (sb + 1) < total;
    if (haveNext) {
      const int sn = sb + 1;
      stage_load((sn < ph1) ? (k0A + sn) : (sn - ph1));   // T14: issue early
    }
    const int kstep = (sb < ph1) ? (k0A + sb) : (sb - ph1);

    if (kstep < nsW) {
      const unsigned char* Kt = KT[buf];
      const int swzr = 16 * (ln & 7);

      f32x4 st[4];
#pragma unroll
      for (int kt = 0; kt < 4; ++kt) {
        const unsigned char* kr = Kt + (16 * kt + ln) * 128;
        const bf16x8 kfa = *(const bf16x8*)(kr + ((16 * lg) ^ swzr));
        const bf16x8 kfb = *(const bf16x8*)(kr + ((16 * lg + 64) ^ swzr));
        f32x4 s = (f32x4){0.f, 0.f, 0.f, 0.f};
        s = __builtin_amdgcn_mfma_f32_16x16x32_bf16(kfa, qf0, s, 0, 0, 0);
        s = __builtin_amdgcn_mfma_f32_16x16x32_bf16(kfb, qf1, s, 0, 0, 0);
        st[kt] = s;
      }

      float x[16];
#pragma unroll
      for (int kt = 0; kt < 4; ++kt)
#pragma unroll
        for (int r = 0; r < 4; ++r) x[4 * kt + r] = st[kt][r];

      if (kstep == nsW - 1) {                // diagonal tile
        const int kv0 = kstep * 64;
        const int qr = qrow0 + ln;
#pragma unroll
        for (int kt = 0; kt < 4; ++kt)
#pragma unroll
          for (int r = 0; r < 4; ++r) {
            const int key = kv0 + 16 * kt + d0 + r;
            if (key > qr) x[4 * kt + r] = -1e30f;
          }
      }

      // per-lane max (tree); rescale only on rare threshold breach
      float t8[8];
#pragma unroll
      for (int e = 0; e < 8; ++e) t8[e] = fmaxf(x[e], x[8 + e]);
      float t4a = fmaxf(t8[0], t8[4]), t4b = fmaxf(t8[1], t8[5]);
      float t4c = fmaxf(t8[2], t8[6]), t4d = fmaxf(t8[3], t8[7]);
      float mx = fmaxf(fmaxf(t4a, t4b), fmaxf(t4c, t4d));

      if (!__all(mx <= m + THR2)) {
        float gm = fmaxf(mx, __shfl_xor(mx, 16, 64));
        gm = fmaxf(gm, __shfl_xor(gm, 32, 64));
        const float newm = fmaxf(m, gm);
        const float sc = __builtin_exp2f(m - newm);
        lsum *= sc;
        float scr[4];
#pragma unroll
        for (int r = 0; r < 4; ++r) scr[r] = __shfl(sc, d0 + r, 64);
#pragma unroll
        for (int nt = 0; nt < 4; ++nt) {
          acc[nt][0] *= scr[0]; acc[nt][1] *= scr[1];
          acc[nt][2] *= scr[2]; acc[nt][3] *= scr[3];
        }
        m = newm;
      }

      float p[16];
#pragma unroll
      for (int e = 0; e < 16; ++e) p[e] = __builtin_exp2f(x[e] - m);
      {
        float s8[8];
#pragma unroll
        for (int e = 0; e < 8; ++e) s8[e] = p[e] + p[8 + e];
        float s4a = s8[0] + s8[4], s4b = s8[1] + s8[5];
        float s4c = s8[2] + s8[6], s4d = s8[3] + s8[7];
        lsum += (s4a + s4b) + (s4c + s4d);
      }

      // PV: 2 key-groups x 4 dim-tiles, V frag = one b128
      const unsigned char* Vt = VT[buf];
#pragma unroll
      for (int kg = 0; kg < 2; ++kg) {
        union { bf16x8 v8; unsigned u[4]; } pf;
#pragma unroll
        for (int j = 0; j < 4; ++j)
          pf.u[j] = cvt2(p[8 * kg + 2 * j], p[8 * kg + 2 * j + 1]);
#pragma unroll
        for (int nt = 0; nt < 4; ++nt) {
          const int row = ln + 16 * nt;
          const bf16x8 vf = *(const bf16x8*)(
              Vt + row * 128 + 16 * ((lg + 4 * kg) ^ (ln & 7)));
          acc[nt] = __builtin_amdgcn_mfma_f32_16x16x32_bf16(pf.v8, vf, acc[nt], 0, 0, 0);
        }
      }
    }

    if (sb == ph1 - 1) {                     // phase boundary (block-uniform)
      epilogue();
#pragma unroll
      for (int nt = 0; nt < 4; ++nt) acc[nt] = (f32x4){0.f, 0.f, 0.f, 0.f};
      m = -1e30f; lsum = 0.f;
      grp = v; curFin = finB; curSlot = slotB;
      qrow0 = grp * 128 + wv * 16;
      nsW = (qrow0 + 79) >> 6;
      load_q();
    }

    if (haveNext) stage_write(buf ^ 1);
    __syncthreads();
    buf ^= 1;
  }

  epilogue();
}

// Merge 2-4 bf16-packed partials per row for groups 4..15.
__global__ __launch_bounds__(256)
void fa_merge(const float* __restrict__ ws, float* __restrict__ O)
{
  const int bi  = (int)blockIdx.x;          // 12*32*8 = 3072
  const int sub = bi & 7;
  const int pr  = bi >> 3;                  // 0..383
  const int gi  = pr >> 5, bh = pr & 31;
  const int tid = (int)threadIdx.x;
  const int d4  = tid & 15;                 // dims 4*d4..+3
  const int row = sub * 16 + (tid >> 4);    // 0..127

  const int Gt[12] = {4,5,6,7, 8,9,10,11, 12,13,14,15};
  const int nS[12] = {2,2,2,2, 3,3,3,3,    4,4,4,4};
  const int S0[12] = {0,0,0,0, 2,2,2,2,    1,1,1,1};
  const int S1[12] = {1,1,1,1, 3,3,3,3,    2,2,2,2};
  const int S2[12] = {0,0,0,0, 4,4,4,4,    3,3,3,3};
  const int S3[12] = {0,0,0,0, 0,0,0,0,    4,4,4,4};

  const int G  = Gt[gi];
  const int n  = nS[gi];
  const int pp = (G <= 7) ? G : (15 - G);
  int sl[4] = {S0[gi], S1[gi], S2[gi], S3[gi]};

  float mv[4], lv[4];
#pragma unroll
  for (int i = 0; i < 4; ++i) {
    if (i < n) {
      const size_t mi = (((size_t)sl[i] * 32 + bh) * 8 + pp) * 128 + row;
      mv[i] = ws[MOFF + mi]; lv[i] = ws[LOFF + mi];
    } else { mv[i] = -1e30f; lv[i] = 0.f; }
  }
  float M = fmaxf(fmaxf(mv[0], mv[1]), fmaxf(mv[2], mv[3]));
  float w[4]; float den = 0.f;
#pragma unroll
  for (int i = 0; i < 4; ++i) {
    w[i] = (i < n) ? __builtin_exp2f(mv[i] - M) : 0.f;
    den += lv[i] * w[i];
  }
  const float inv = 1.0f / den;

  // acc gather (R12-proven layout): value (row,dim) at wave row>>4, lane
  // lgq*16+ln (lgq=(row&15)>>2, ln=dim&15), uint nt*2+rp, half rlo.
  const int wvq = row >> 4, lgq = (row & 15) >> 2, r = row & 3;
  const int rp = r >> 1, rlo = r & 1;
  const unsigned short* wsh = (const unsigned short*)ws;
  float o[4] = {0.f, 0.f, 0.f, 0.f};
#pragma unroll
  for (int i = 0; i < 4; ++i) {
    if (i >= n) break;
    const size_t base_u =
        ((((size_t)sl[i] * 32 + bh) * 8 + pp) * 8 + wvq) * 512;
#pragma unroll
    for (int j = 0; j < 4; ++j) {
      const int dim = 4 * d4 + j;
      const int ln = dim & 15, nt = dim >> 4;
      const size_t ua = base_u + (size_t)(lgq * 16 + ln) * 8 + nt * 2 + rp;
      o[j] += bf2f(wsh[ua * 2 + rlo]) * w[i];
    }
  }

  const int b = bh >> 3, h = bh & 7;
  const size_t off = ((size_t)(b * L + G * 128 + row) * H + h) * E + 4 * d4;
  float4 ov; ov.x = o[0] * inv; ov.y = o[1] * inv; ov.z = o[2] * inv; ov.w = o[3] * inv;
  *(float4*)(O + off) = ov;
}

} // namespace

extern "C" void kernel_launch(void* const* d_in, const int* in_sizes, int n_in,
                              void* d_out, int out_size, void* d_ws, size_t ws_size,
                              hipStream_t stream) {
  const float* Q = (const float*)d_in[0];
  const float* K = (const float*)d_in[1];
  const float* V = (const float*)d_in[2];
  float* O = (float*)d_out;
  (void)in_sizes; (void)n_in; (void)out_size;

  const bool split = ws_size >= WS_FLOATS * sizeof(float);
  if (split) {
    fa_split<<<1024, 512, 0, stream>>>(Q, K, V, O, (float*)d_ws, 1);
    fa_merge<<<3072, 256, 0, stream>>>((const float*)d_ws, O);
  } else {
    fa_split<<<256, 512, 0, stream>>>(Q, K, V, O, (float*)d_ws, 0);
  }
}

// Round 16
// 53.521 us; speedup vs baseline: 1.2014x; 1.1254x over previous
//
#include <hip/hip_runtime.h>
#include <hip/hip_bf16.h>

namespace {

constexpr int B_ = 4, L = 2048, H = 8, E = 64;
constexpr int RS = H * E;            // 512 floats: row stride in [B,L,H,E]
constexpr float CS = 0.125f * 1.44269504f;  // SCALE * log2(e): exp2-direct
constexpr float THR2 = 11.5f;        // defer-max threshold in log2 units

// split-K partials (floats): acc[2][32][1024rows][64] ++ m ++ l  (R11 layout)
constexpr size_t ACCF = (size_t)2 * 32 * 8 * 128 * 64;
constexpr size_t MOFF = ACCF;
constexpr size_t PART_ROWS = (size_t)32 * 8 * 128;
constexpr size_t LOFF = MOFF + 2 * PART_ROWS;
constexpr size_t PART_FLOATS = LOFF + 2 * PART_ROWS;   // ~17.3 MB

typedef __attribute__((ext_vector_type(8))) short bf16x8;
typedef __attribute__((ext_vector_type(4))) float f32x4;

__device__ inline unsigned cvt2(float a, float b) {
  __hip_bfloat162 hh = __float22bfloat162_rn(make_float2(a, b));  // v_cvt_pk_bf16_f32
  union { __hip_bfloat162 h; unsigned u; } c; c.h = hh; return c.u;
}

// R11 structure (512 blocks x 8 waves, pair (g,15-g), two uniform 17-step
// roles, QBLK=16, KVBLK=64) with ONE isolated change vs R11:
//   lsum computed via a ones-column PV MFMA (acc4) instead of a per-lane
//   VALU sum tree + epilogue shfl reduce. Everything else verbatim R11.
__global__ __launch_bounds__(512)
void fa_split(const float* __restrict__ Q, const float* __restrict__ K,
              const float* __restrict__ V, float* __restrict__ O,
              float* __restrict__ ws, int splitMode)
{
  const int tid  = (int)threadIdx.x;
  const int lane = tid & 63;
  const int wv   = tid >> 6;
  const int bi   = (int)blockIdx.x;
  const int bh   = bi & 31;                 // low bits -> XCD L2 locality
  const int pp   = (bi >> 5) & 7;
  const int role = splitMode ? (bi >> 8) : 2;
  const int b = bh >> 3, h = bh & 7;
  const int ln = lane & 15, lg = lane >> 4, d0 = lg * 4;

  // schedule (64-key steps)
  int total, ph1sb0, qgA, k0A, qgB; bool finA, finB; int part;
  const int g = pp, v = 15 - pp;
  if (role == 0)      { total = 17; ph1sb0 = 2*g+2; qgA = g; k0A = 0;        finA = true;  qgB = v; finB = false; part = 0; }
  else if (role == 1) { total = 17; ph1sb0 = 1000;  qgA = v; k0A = 15 - 2*g; finA = false; qgB = 0; finB = false; part = 1; }
  else                { total = 34; ph1sb0 = 2*g+2; qgA = g; k0A = 0;        finA = true;  qgB = v; finB = true;  part = 0; }

  const size_t base = (size_t)b * L * RS + (size_t)h * E;
  const float* Qb = Q + base;
  const float* Kb = K + base;
  const float* Vb = V + base;
  float*       Ob = O + base;

  __shared__ __align__(16) unsigned char KT[2][64 * 128];
  __shared__ __align__(16) unsigned char VT[2][64 * 128];

  // ---- staging (verbatim R11) ----
  const int vdd = tid & 63, vc = tid >> 6;          // V: dim vdd, chunk vc
  const int vkb = 4 * vc + ((vc >> 2) << 4);        // keys vkb..+3, vkb+16..+19
  const int kky = tid >> 3, kc = tid & 7;           // K: key kky, dims 8kc..+7
  float vr[8]; float4 kr0, kr1;

  auto stage_load = [&](int ks) {
    const int kv0 = ks * 64;
    const float* vp = Vb + (size_t)(kv0 + vkb) * RS + vdd;
#pragma unroll
    for (int j = 0; j < 4; ++j) vr[j] = vp[(size_t)j * RS];
#pragma unroll
    for (int j = 0; j < 4; ++j) vr[4 + j] = vp[(size_t)(16 + j) * RS];
    const float* kp = Kb + (size_t)(kv0 + kky) * RS + 8 * kc;
    kr0 = *(const float4*)kp; kr1 = *(const float4*)(kp + 4);
  };
  auto stage_write = [&](int bufI) {
    union { uint4 q; unsigned u[4]; } w;
    w.u[0] = cvt2(vr[0], vr[1]); w.u[1] = cvt2(vr[2], vr[3]);
    w.u[2] = cvt2(vr[4], vr[5]); w.u[3] = cvt2(vr[6], vr[7]);
    *(uint4*)(VT[bufI] + vdd * 128 + 16 * (vc ^ (vdd & 7))) = w.q;
    union { uint4 q; unsigned u[4]; } y;
    y.u[0] = cvt2(kr0.x, kr0.y); y.u[1] = cvt2(kr0.z, kr0.w);
    y.u[2] = cvt2(kr1.x, kr1.y); y.u[3] = cvt2(kr1.z, kr1.w);
    *(uint4*)(KT[bufI] + kky * 128 + 16 * (kc ^ (kky & 7))) = y.q;
  };

  // ---- per-phase state ----
  int qg = qgA; bool curFin = finA;
  int qrow0 = qg * 128 + wv * 16;
  int nsW   = (qrow0 + 79) >> 6;

  bf16x8 qf0, qf1;
  auto load_q = [&]() {                      // Q pre-scaled by CS (exp2 domain)
    const float* qp = Qb + (size_t)(qrow0 + ln) * RS + 8 * lg;
    float4 a = *(const float4*)qp,        c = *(const float4*)(qp + 4);
    float4 d = *(const float4*)(qp + 32), e = *(const float4*)(qp + 36);
    union { bf16x8 v8; unsigned u[4]; } r0, r1;
    r0.u[0] = cvt2(a.x * CS, a.y * CS); r0.u[1] = cvt2(a.z * CS, a.w * CS);
    r0.u[2] = cvt2(c.x * CS, c.y * CS); r0.u[3] = cvt2(c.z * CS, c.w * CS);
    r1.u[0] = cvt2(d.x * CS, d.y * CS); r1.u[1] = cvt2(d.z * CS, d.w * CS);
    r1.u[2] = cvt2(e.x * CS, e.y * CS); r1.u[3] = cvt2(e.z * CS, e.w * CS);
    qf0 = r0.v8; qf1 = r1.v8;
  };
  load_q();

  // ones fragment for the lsum column (bf16 1.0 = 0x3F80)
  union { bf16x8 v8; unsigned u[4]; } ones;
#pragma unroll
  for (int j = 0; j < 4; ++j) ones.u[j] = 0x3F803F80u;

  f32x4 acc[4], acc4;
#pragma unroll
  for (int nt = 0; nt < 4; ++nt) acc[nt] = (f32x4){0.f, 0.f, 0.f, 0.f};
  acc4 = (f32x4){0.f, 0.f, 0.f, 0.f};       // acc4[r] = lsum of q-row d0+r
  float m = -1e30f;

  auto epilogue = [&]() {
    if (curFin) {
#pragma unroll
      for (int r = 0; r < 4; ++r) {
        const float il = 1.0f / acc4[r];
#pragma unroll
        for (int nt = 0; nt < 4; ++nt)
          Ob[(size_t)(qrow0 + d0 + r) * RS + (ln + 16 * nt)] = acc[nt][r] * il;
      }
    } else {
      const int vg = qg - 8;
      const size_t rb = ((size_t)part * 32 + bh) * 1024 + (size_t)vg * 128;
#pragma unroll
      for (int nt = 0; nt < 4; ++nt)
#pragma unroll
        for (int r = 0; r < 4; ++r)
          ws[(rb + wv * 16 + d0 + r) * 64 + ln + 16 * nt] = acc[nt][r];
      if (lane < 16) ws[MOFF + rb + wv * 16 + lane] = m;
      if (ln == 0) {
#pragma unroll
        for (int r = 0; r < 4; ++r)
          ws[LOFF + rb + wv * 16 + d0 + r] = acc4[r];
      }
    }
  };

  stage_load(k0A);
  stage_write(0);
  __syncthreads();
  int buf = 0;

  for (int sb = 0; sb < total; ++sb) {
    const bool haveNext = (sb + 1) < total;
    if (haveNext) {
      const int sn = sb + 1;
      stage_load((sn < ph1sb0) ? (k0A + sn) : (sn - ph1sb0));   // T14: issue early
    }
    const int kstep = (sb < ph1sb0) ? (k0A + sb) : (sb - ph1sb0);

    if (kstep < nsW) {
      const unsigned char* Kt = KT[buf];
      const int swzr = 16 * (ln & 7);

      f32x4 st[4];
#pragma unroll
      for (int kt = 0; kt < 4; ++kt) {
        const unsigned char* kr = Kt + (16 * kt + ln) * 128;
        const bf16x8 kfa = *(const bf16x8*)(kr + ((16 * lg) ^ swzr));
        const bf16x8 kfb = *(const bf16x8*)(kr + ((16 * lg + 64) ^ swzr));
        f32x4 s = (f32x4){0.f, 0.f, 0.f, 0.f};
        s = __builtin_amdgcn_mfma_f32_16x16x32_bf16(kfa, qf0, s, 0, 0, 0);
        s = __builtin_amdgcn_mfma_f32_16x16x32_bf16(kfb, qf1, s, 0, 0, 0);
        st[kt] = s;
      }

      float x[16];
#pragma unroll
      for (int kt = 0; kt < 4; ++kt)
#pragma unroll
        for (int r = 0; r < 4; ++r) x[4 * kt + r] = st[kt][r];

      if (kstep == nsW - 1) {                // diagonal tile
        const int kv0 = kstep * 64;
        const int qr = qrow0 + ln;
#pragma unroll
        for (int kt = 0; kt < 4; ++kt)
#pragma unroll
          for (int r = 0; r < 4; ++r) {
            const int key = kv0 + 16 * kt + d0 + r;
            if (key > qr) x[4 * kt + r] = -1e30f;
          }
      }

      // per-lane max (tree); rescale only on rare threshold breach
      float t8[8];
#pragma unroll
      for (int e = 0; e < 8; ++e) t8[e] = fmaxf(x[e], x[8 + e]);
      float t4a = fmaxf(t8[0], t8[4]), t4b = fmaxf(t8[1], t8[5]);
      float t4c = fmaxf(t8[2], t8[6]), t4d = fmaxf(t8[3], t8[7]);
      float mx = fmaxf(fmaxf(t4a, t4b), fmaxf(t4c, t4d));

      if (!__all(mx <= m + THR2)) {
        float gm = fmaxf(mx, __shfl_xor(mx, 16, 64));
        gm = fmaxf(gm, __shfl_xor(gm, 32, 64));
        const float newm = fmaxf(m, gm);
        const float sc = __builtin_exp2f(m - newm);
        float scr[4];
#pragma unroll
        for (int r = 0; r < 4; ++r) scr[r] = __shfl(sc, d0 + r, 64);
#pragma unroll
        for (int nt = 0; nt < 4; ++nt) {
          acc[nt][0] *= scr[0]; acc[nt][1] *= scr[1];
          acc[nt][2] *= scr[2]; acc[nt][3] *= scr[3];
        }
        acc4[0] *= scr[0]; acc4[1] *= scr[1];
        acc4[2] *= scr[2]; acc4[3] *= scr[3];
        m = newm;
      }

      float p[16];
#pragma unroll
      for (int e = 0; e < 16; ++e) p[e] = __builtin_exp2f(x[e] - m);

      // PV (+ ones column for lsum): 2 key-groups x (4 dim-tiles + 1)
      const unsigned char* Vt = VT[buf];
#pragma unroll
      for (int kg = 0; kg < 2; ++kg) {
        union { bf16x8 v8; unsigned u[4]; } pf;
#pragma unroll
        for (int j = 0; j < 4; ++j)
          pf.u[j] = cvt2(p[8 * kg + 2 * j], p[8 * kg + 2 * j + 1]);
#pragma unroll
        for (int nt = 0; nt < 4; ++nt) {
          const int row = ln + 16 * nt;
          const bf16x8 vf = *(const bf16x8*)(
              Vt + row * 128 + 16 * ((lg + 4 * kg) ^ (ln & 7)));
          acc[nt] = __builtin_amdgcn_mfma_f32_16x16x32_bf16(pf.v8, vf, acc[nt], 0, 0, 0);
        }
        acc4 = __builtin_amdgcn_mfma_f32_16x16x32_bf16(pf.v8, ones.v8, acc4, 0, 0, 0);
      }
    }

    if (sb == ph1sb0 - 1) {                  // phase boundary (block-uniform)
      epilogue();
#pragma unroll
      for (int nt = 0; nt < 4; ++nt) acc[nt] = (f32x4){0.f, 0.f, 0.f, 0.f};
      acc4 = (f32x4){0.f, 0.f, 0.f, 0.f};
      m = -1e30f;
      qg = qgB; curFin = finB;
      qrow0 = qg * 128 + wv * 16;
      nsW = (qrow0 + 79) >> 6;
      load_q();
    }

    if (haveNext) stage_write(buf ^ 1);
    __syncthreads();
    buf ^= 1;
  }

  epilogue();
}

// Combine the two split-K partials for rows 1024..2047 (VERBATIM from R11).
__global__ __launch_bounds__(256)
void fa_merge(const float* __restrict__ ws, float* __restrict__ O)
{
  const int idx = (int)blockIdx.x * 256 + (int)threadIdx.x;   // 0..524287
  const int d4  = idx & 15;
  const int row = (idx >> 4) & 127;
  const int vg  = (idx >> 11) & 7;
  const int bh  = idx >> 14;
  const size_t rbase = ((size_t)bh * 8 + vg) * 128 + row;

  const float m0 = ws[MOFF + rbase],             l0 = ws[LOFF + rbase];
  const float m1 = ws[MOFF + PART_ROWS + rbase], l1 = ws[LOFF + PART_ROWS + rbase];
  const float M  = fmaxf(m0, m1);
  const float e0 = __builtin_exp2f(m0 - M), e1 = __builtin_exp2f(m1 - M);
  const float inv = 1.0f / (l0 * e0 + l1 * e1);

  const float4 a0 = *(const float4*)(ws + rbase * 64 + 4 * d4);
  const float4 a1 = *(const float4*)(ws + PART_ROWS * 64 + rbase * 64 + 4 * d4);

  const int b = bh >> 3, h = bh & 7;
  const int orow = (8 + vg) * 128 + row;
  float4 o;
  o.x = (a0.x * e0 + a1.x * e1) * inv;
  o.y = (a0.y * e0 + a1.y * e1) * inv;
  o.z = (a0.z * e0 + a1.z * e1) * inv;
  o.w = (a0.w * e0 + a1.w * e1) * inv;
  *(float4*)(O + ((size_t)(b * L + orow) * H + h) * E + 4 * d4) = o;
}

} // namespace

extern "C" void kernel_launch(void* const* d_in, const int* in_sizes, int n_in,
                              void* d_out, int out_size, void* d_ws, size_t ws_size,
                              hipStream_t stream) {
  const float* Q = (const float*)d_in[0];
  const float* K = (const float*)d_in[1];
  const float* V = (const float*)d_in[2];
  float* O = (float*)d_out;
  (void)in_sizes; (void)n_in; (void)out_size;

  const bool split = ws_size >= PART_FLOATS * sizeof(float);
  if (split) {
    fa_split<<<512, 512, 0, stream>>>(Q, K, V, O, (float*)d_ws, 1);
    fa_merge<<<2048, 256, 0, stream>>>((const float*)d_ws, O);
  } else {
    fa_split<<<256, 512, 0, stream>>>(Q, K, V, O, (float*)d_ws, 0);
  }
}

// Round 17
// 49.887 us; speedup vs baseline: 1.2889x; 1.0728x over previous
//
#include <hip/hip_runtime.h>
#include <hip/hip_bf16.h>

namespace {

constexpr int B_ = 4, L = 2048, H = 8, E = 64;
constexpr int RS = H * E;            // 512 floats: row stride in [B,L,H,E]
constexpr float CS = 0.125f * 1.44269504f;  // SCALE * log2(e): exp2-direct
constexpr float THR2 = 11.5f;        // defer-max threshold in log2 units

// split-K partials (floats): acc[2][32][1024rows][64] ++ m ++ l  (R11 layout)
constexpr size_t ACCF = (size_t)2 * 32 * 8 * 128 * 64;
constexpr size_t MOFF = ACCF;
constexpr size_t PART_ROWS = (size_t)32 * 8 * 128;
constexpr size_t LOFF = MOFF + 2 * PART_ROWS;
constexpr size_t PART_FLOATS = LOFF + 2 * PART_ROWS;   // ~17.3 MB

typedef __attribute__((ext_vector_type(8))) short bf16x8;
typedef __attribute__((ext_vector_type(4))) float f32x4;

__device__ inline unsigned cvt2(float a, float b) {
  __hip_bfloat162 hh = __float22bfloat162_rn(make_float2(a, b));  // v_cvt_pk_bf16_f32
  union { __hip_bfloat162 h; unsigned u; } c; c.h = hh; return c.u;
}

// R16 base (512 blocks x 8 waves, pair (g,15-g), two uniform 17-step roles,
// QBLK=16, KVBLK=64, ones-column lsum) with two micro-cuts:
//  1. s_setprio(1) around the QK->PV compute region (T5: 2 blocks/CU at
//     different phases -> wave role diversity -> arbitration pays).
//  2. Incremental staging pointers (+= 64*RS per step) instead of per-step
//     address rebuild; rebuilt only at the phase boundary.
__global__ __launch_bounds__(512)
void fa_split(const float* __restrict__ Q, const float* __restrict__ K,
              const float* __restrict__ V, float* __restrict__ O,
              float* __restrict__ ws, int splitMode)
{
  const int tid  = (int)threadIdx.x;
  const int lane = tid & 63;
  const int wv   = tid >> 6;
  const int bi   = (int)blockIdx.x;
  const int bh   = bi & 31;                 // low bits -> XCD L2 locality
  const int pp   = (bi >> 5) & 7;
  const int role = splitMode ? (bi >> 8) : 2;
  const int b = bh >> 3, h = bh & 7;
  const int ln = lane & 15, lg = lane >> 4, d0 = lg * 4;

  // schedule (64-key steps)
  int total, ph1sb0, qgA, k0A, qgB; bool finA, finB; int part;
  const int g = pp, v = 15 - pp;
  if (role == 0)      { total = 17; ph1sb0 = 2*g+2; qgA = g; k0A = 0;        finA = true;  qgB = v; finB = false; part = 0; }
  else if (role == 1) { total = 17; ph1sb0 = 1000;  qgA = v; k0A = 15 - 2*g; finA = false; qgB = 0; finB = false; part = 1; }
  else                { total = 34; ph1sb0 = 2*g+2; qgA = g; k0A = 0;        finA = true;  qgB = v; finB = true;  part = 0; }

  const size_t base = (size_t)b * L * RS + (size_t)h * E;
  const float* Qb = Q + base;
  const float* Kb = K + base;
  const float* Vb = V + base;
  float*       Ob = O + base;

  __shared__ __align__(16) unsigned char KT[2][64 * 128];
  __shared__ __align__(16) unsigned char VT[2][64 * 128];

  // ---- staging: incremental pointers, one uint4 LDS write each ----
  const int vdd = tid & 63, vc = tid >> 6;          // V: dim vdd, chunk vc
  const int vkb = 4 * vc + ((vc >> 2) << 4);        // keys vkb..+3, vkb+16..+19
  const int kky = tid >> 3, kc = tid & 7;           // K: key kky, dims 8kc..+7
  float vr[8]; float4 kr0, kr1;
  const float* vp_it;                                // incremental cursors
  const float* kp_it;

  auto stage_seek = [&](int ks) {                    // rebuild cursors (rare)
    const int kv0 = ks * 64;
    vp_it = Vb + (size_t)(kv0 + vkb) * RS + vdd;
    kp_it = Kb + (size_t)(kv0 + kky) * RS + 8 * kc;
  };
  auto stage_load = [&]() {                          // load at cursor, advance
#pragma unroll
    for (int j = 0; j < 4; ++j) vr[j] = vp_it[(size_t)j * RS];
#pragma unroll
    for (int j = 0; j < 4; ++j) vr[4 + j] = vp_it[(size_t)(16 + j) * RS];
    kr0 = *(const float4*)kp_it; kr1 = *(const float4*)(kp_it + 4);
    vp_it += (size_t)64 * RS;
    kp_it += (size_t)64 * RS;
  };
  auto stage_write = [&](int bufI) {
    union { uint4 q; unsigned u[4]; } w;
    w.u[0] = cvt2(vr[0], vr[1]); w.u[1] = cvt2(vr[2], vr[3]);
    w.u[2] = cvt2(vr[4], vr[5]); w.u[3] = cvt2(vr[6], vr[7]);
    *(uint4*)(VT[bufI] + vdd * 128 + 16 * (vc ^ (vdd & 7))) = w.q;
    union { uint4 q; unsigned u[4]; } y;
    y.u[0] = cvt2(kr0.x, kr0.y); y.u[1] = cvt2(kr0.z, kr0.w);
    y.u[2] = cvt2(kr1.x, kr1.y); y.u[3] = cvt2(kr1.z, kr1.w);
    *(uint4*)(KT[bufI] + kky * 128 + 16 * (kc ^ (kky & 7))) = y.q;
  };

  // ---- per-phase state ----
  int qg = qgA; bool curFin = finA;
  int qrow0 = qg * 128 + wv * 16;
  int nsW   = (qrow0 + 79) >> 6;

  bf16x8 qf0, qf1;
  auto load_q = [&]() {                      // Q pre-scaled by CS (exp2 domain)
    const float* qp = Qb + (size_t)(qrow0 + ln) * RS + 8 * lg;
    float4 a = *(const float4*)qp,        c = *(const float4*)(qp + 4);
    float4 d = *(const float4*)(qp + 32), e = *(const float4*)(qp + 36);
    union { bf16x8 v8; unsigned u[4]; } r0, r1;
    r0.u[0] = cvt2(a.x * CS, a.y * CS); r0.u[1] = cvt2(a.z * CS, a.w * CS);
    r0.u[2] = cvt2(c.x * CS, c.y * CS); r0.u[3] = cvt2(c.z * CS, c.w * CS);
    r1.u[0] = cvt2(d.x * CS, d.y * CS); r1.u[1] = cvt2(d.z * CS, d.w * CS);
    r1.u[2] = cvt2(e.x * CS, e.y * CS); r1.u[3] = cvt2(e.z * CS, e.w * CS);
    qf0 = r0.v8; qf1 = r1.v8;
  };
  load_q();

  // ones fragment for the lsum column (bf16 1.0 = 0x3F80)
  union { bf16x8 v8; unsigned u[4]; } ones;
#pragma unroll
  for (int j = 0; j < 4; ++j) ones.u[j] = 0x3F803F80u;

  f32x4 acc[4], acc4;
#pragma unroll
  for (int nt = 0; nt < 4; ++nt) acc[nt] = (f32x4){0.f, 0.f, 0.f, 0.f};
  acc4 = (f32x4){0.f, 0.f, 0.f, 0.f};       // acc4[r] = lsum of q-row d0+r
  float m = -1e30f;

  auto epilogue = [&]() {
    if (curFin) {
#pragma unroll
      for (int r = 0; r < 4; ++r) {
        const float il = 1.0f / acc4[r];
#pragma unroll
        for (int nt = 0; nt < 4; ++nt)
          Ob[(size_t)(qrow0 + d0 + r) * RS + (ln + 16 * nt)] = acc[nt][r] * il;
      }
    } else {
      const int vg = qg - 8;
      const size_t rb = ((size_t)part * 32 + bh) * 1024 + (size_t)vg * 128;
#pragma unroll
      for (int nt = 0; nt < 4; ++nt)
#pragma unroll
        for (int r = 0; r < 4; ++r)
          ws[(rb + wv * 16 + d0 + r) * 64 + ln + 16 * nt] = acc[nt][r];
      if (lane < 16) ws[MOFF + rb + wv * 16 + lane] = m;
      if (ln == 0) {
#pragma unroll
        for (int r = 0; r < 4; ++r)
          ws[LOFF + rb + wv * 16 + d0 + r] = acc4[r];
      }
    }
  };

  stage_seek(k0A);
  stage_load();
  stage_write(0);
  __syncthreads();
  int buf = 0;

  for (int sb = 0; sb < total; ++sb) {
    const bool haveNext = (sb + 1) < total;
    if (haveNext) {
      if (sb + 1 == ph1sb0) stage_seek(0);   // phase-B restart (rare)
      stage_load();                          // T14: issue early
    }
    const int kstep = (sb < ph1sb0) ? (k0A + sb) : (sb - ph1sb0);

    if (kstep < nsW) {
      __builtin_amdgcn_s_setprio(1);         // T5: favor compute waves
      const unsigned char* Kt = KT[buf];
      const int swzr = 16 * (ln & 7);

      f32x4 st[4];
#pragma unroll
      for (int kt = 0; kt < 4; ++kt) {
        const unsigned char* kr = Kt + (16 * kt + ln) * 128;
        const bf16x8 kfa = *(const bf16x8*)(kr + ((16 * lg) ^ swzr));
        const bf16x8 kfb = *(const bf16x8*)(kr + ((16 * lg + 64) ^ swzr));
        f32x4 s = (f32x4){0.f, 0.f, 0.f, 0.f};
        s = __builtin_amdgcn_mfma_f32_16x16x32_bf16(kfa, qf0, s, 0, 0, 0);
        s = __builtin_amdgcn_mfma_f32_16x16x32_bf16(kfb, qf1, s, 0, 0, 0);
        st[kt] = s;
      }

      float x[16];
#pragma unroll
      for (int kt = 0; kt < 4; ++kt)
#pragma unroll
        for (int r = 0; r < 4; ++r) x[4 * kt + r] = st[kt][r];

      if (kstep == nsW - 1) {                // diagonal tile
        const int kv0 = kstep * 64;
        const int qr = qrow0 + ln;
#pragma unroll
        for (int kt = 0; kt < 4; ++kt)
#pragma unroll
          for (int r = 0; r < 4; ++r) {
            const int key = kv0 + 16 * kt + d0 + r;
            if (key > qr) x[4 * kt + r] = -1e30f;
          }
      }

      // per-lane max (tree); rescale only on rare threshold breach
      float t8[8];
#pragma unroll
      for (int e = 0; e < 8; ++e) t8[e] = fmaxf(x[e], x[8 + e]);
      float t4a = fmaxf(t8[0], t8[4]), t4b = fmaxf(t8[1], t8[5]);
      float t4c = fmaxf(t8[2], t8[6]), t4d = fmaxf(t8[3], t8[7]);
      float mx = fmaxf(fmaxf(t4a, t4b), fmaxf(t4c, t4d));

      if (!__all(mx <= m + THR2)) {
        float gm = fmaxf(mx, __shfl_xor(mx, 16, 64));
        gm = fmaxf(gm, __shfl_xor(gm, 32, 64));
        const float newm = fmaxf(m, gm);
        const float sc = __builtin_exp2f(m - newm);
        float scr[4];
#pragma unroll
        for (int r = 0; r < 4; ++r) scr[r] = __shfl(sc, d0 + r, 64);
#pragma unroll
        for (int nt = 0; nt < 4; ++nt) {
          acc[nt][0] *= scr[0]; acc[nt][1] *= scr[1];
          acc[nt][2] *= scr[2]; acc[nt][3] *= scr[3];
        }
        acc4[0] *= scr[0]; acc4[1] *= scr[1];
        acc4[2] *= scr[2]; acc4[3] *= scr[3];
        m = newm;
      }

      float p[16];
#pragma unroll
      for (int e = 0; e < 16; ++e) p[e] = __builtin_exp2f(x[e] - m);

      // PV (+ ones column for lsum): 2 key-groups x (4 dim-tiles + 1)
      const unsigned char* Vt = VT[buf];
#pragma unroll
      for (int kg = 0; kg < 2; ++kg) {
        union { bf16x8 v8; unsigned u[4]; } pf;
#pragma unroll
        for (int j = 0; j < 4; ++j)
          pf.u[j] = cvt2(p[8 * kg + 2 * j], p[8 * kg + 2 * j + 1]);
#pragma unroll
        for (int nt = 0; nt < 4; ++nt) {
          const int row = ln + 16 * nt;
          const bf16x8 vf = *(const bf16x8*)(
              Vt + row * 128 + 16 * ((lg + 4 * kg) ^ (ln & 7)));
          acc[nt] = __builtin_amdgcn_mfma_f32_16x16x32_bf16(pf.v8, vf, acc[nt], 0, 0, 0);
        }
        acc4 = __builtin_amdgcn_mfma_f32_16x16x32_bf16(pf.v8, ones.v8, acc4, 0, 0, 0);
      }
      __builtin_amdgcn_s_setprio(0);
    }

    if (sb == ph1sb0 - 1) {                  // phase boundary (block-uniform)
      epilogue();
#pragma unroll
      for (int nt = 0; nt < 4; ++nt) acc[nt] = (f32x4){0.f, 0.f, 0.f, 0.f};
      acc4 = (f32x4){0.f, 0.f, 0.f, 0.f};
      m = -1e30f;
      qg = qgB; curFin = finB;
      qrow0 = qg * 128 + wv * 16;
      nsW = (qrow0 + 79) >> 6;
      load_q();
    }

    if (haveNext) stage_write(buf ^ 1);
    __syncthreads();
    buf ^= 1;
  }

  epilogue();
}

// Combine the two split-K partials for rows 1024..2047 (VERBATIM from R11).
__global__ __launch_bounds__(256)
void fa_merge(const float* __restrict__ ws, float* __restrict__ O)
{
  const int idx = (int)blockIdx.x * 256 + (int)threadIdx.x;   // 0..524287
  const int d4  = idx & 15;
  const int row = (idx >> 4) & 127;
  const int vg  = (idx >> 11) & 7;
  const int bh  = idx >> 14;
  const size_t rbase = ((size_t)bh * 8 + vg) * 128 + row;

  const float m0 = ws[MOFF + rbase],             l0 = ws[LOFF + rbase];
  const float m1 = ws[MOFF + PART_ROWS + rbase], l1 = ws[LOFF + PART_ROWS + rbase];
  const float M  = fmaxf(m0, m1);
  const float e0 = __builtin_exp2f(m0 - M), e1 = __builtin_exp2f(m1 - M);
  const float inv = 1.0f / (l0 * e0 + l1 * e1);

  const float4 a0 = *(const float4*)(ws + rbase * 64 + 4 * d4);
  const float4 a1 = *(const float4*)(ws + PART_ROWS * 64 + rbase * 64 + 4 * d4);

  const int b = bh >> 3, h = bh & 7;
  const int orow = (8 + vg) * 128 + row;
  float4 o;
  o.x = (a0.x * e0 + a1.x * e1) * inv;
  o.y = (a0.y * e0 + a1.y * e1) * inv;
  o.z = (a0.z * e0 + a1.z * e1) * inv;
  o.w = (a0.w * e0 + a1.w * e1) * inv;
  *(float4*)(O + ((size_t)(b * L + orow) * H + h) * E + 4 * d4) = o;
}

} // namespace

extern "C" void kernel_launch(void* const* d_in, const int* in_sizes, int n_in,
                              void* d_out, int out_size, void* d_ws, size_t ws_size,
                              hipStream_t stream) {
  const float* Q = (const float*)d_in[0];
  const float* K = (const float*)d_in[1];
  const float* V = (const float*)d_in[2];
  float* O = (float*)d_out;
  (void)in_sizes; (void)n_in; (void)out_size;

  const bool split = ws_size >= PART_FLOATS * sizeof(float);
  if (split) {
    fa_split<<<512, 512, 0, stream>>>(Q, K, V, O, (float*)d_ws, 1);
    fa_merge<<<2048, 256, 0, stream>>>((const float*)d_ws, O);
  } else {
    fa_split<<<256, 512, 0, stream>>>(Q, K, V, O, (float*)d_ws, 0);
  }
}